// Round 4
// baseline (599.860 us; speedup 1.0000x reference)
//
#include <hip/hip_runtime.h>

// DSR loss, single-pass decoupled-lookback formulation.
// R_t = dot16(w_t, x_t); A_t = c*A_{t-1} + eta*R_t (c=0.99), B_t likewise
// with R_t^2; D_t computed from (A_prev,B_prev); out = -mean(D).
//
// R4: ONE streaming kernel (plus tiny init). Each block takes a ticket
// (dynamic id -> resident blocks always own the lowest unprocessed chunks,
// so lookback cannot deadlock), computes its chunk's dots into LDS, forms
// the chunk's affine transform via block scan, publishes aggregate (flag=1),
// looks back to resolve its exclusive prefix, publishes inclusive prefix
// (flag=2), replays D_t from LDS, and atomically accumulates the fp64 sum.
// The last block to finish writes the final scalar. fp64 internal math
// (bit-exact vs np ref in R1-R3, absmax 0.0).

#define D_ETA 0.01
#define D_C   (1.0 - D_ETA)
#define D_EPS 1e-8

constexpr int BLOCK = 256;
constexpr int CHUNK = 2048;          // rows per chunk
constexpr int LPT   = CHUNK / BLOCK; // 8 rows per thread in scan/replay
constexpr int GRP   = CHUNK / 64;    // 32 row-groups of 64 per chunk

#define SCOPE __HIP_MEMORY_SCOPE_AGENT

__device__ __forceinline__ double dot4d(float4 a, float4 b) {
    return (double)a.x * (double)b.x + (double)a.y * (double)b.y
         + (double)a.z * (double)b.z + (double)a.w * (double)b.w;
}

// Hillis-Steele inclusive scan over 256 affine transforms (m, sA, sB).
// Arrays end up holding the inclusive scan values.
__device__ __forceinline__ void block_scan(double& m, double& sA, double& sB,
                                           double* mS, double* aS, double* bS) {
    int tid = threadIdx.x;
    mS[tid] = m; aS[tid] = sA; bS[tid] = sB;
    __syncthreads();
#pragma unroll
    for (int off = 1; off < BLOCK; off <<= 1) {
        double pm = 1.0, pa = 0.0, pb = 0.0;
        if (tid >= off) { pm = mS[tid - off]; pa = aS[tid - off]; pb = bS[tid - off]; }
        __syncthreads();
        if (tid >= off) {
            sA = m * pa + sA;
            sB = m * pb + sB;
            m  = pm * m;
        }
        mS[tid] = m; aS[tid] = sA; bS[tid] = sB;
        __syncthreads();
    }
}

// ---------------- K0: zero the control block ----------------
__global__ __launch_bounds__(BLOCK) void k0_init(unsigned* __restrict__ ctl,
                                                 int nctl)
{
    int i = blockIdx.x * BLOCK + threadIdx.x;
    if (i < nctl) ctl[i] = 0u;
}

// ---------------- K1: the whole thing ----------------
__global__ __launch_bounds__(BLOCK) void k_mega(
    const float* __restrict__ w, const float* __restrict__ x,
    int nrows, int nb,
    unsigned* __restrict__ ticket,   // [1]
    unsigned* __restrict__ flags,    // [nb]  0=empty 1=agg 2=prefix
    double*   __restrict__ recs,     // [nb*6] agg(m,a,b), prefix(m,a,b)
    double*   __restrict__ acc,      // [1] fp64 D-sum
    unsigned* __restrict__ done,     // [1]
    float*    __restrict__ out)
{
    __shared__ float  Rs[CHUNK];
    __shared__ double mS[BLOCK], aS[BLOCK], bS[BLOCK];
    __shared__ double exA, exB;      // block start state (A,B)
    __shared__ double wsum[BLOCK / 64];
    __shared__ unsigned s_cid;

    int tid = threadIdx.x;
    if (tid == 0)
        s_cid = __hip_atomic_fetch_add(ticket, 1u, __ATOMIC_RELAXED, SCOPE);
    __syncthreads();
    int cid = (int)s_cid;
    long long base = (long long)cid * CHUNK;

    // ---- phase 1: dots -> LDS ----
    int q    = tid & 3;   // float4 index within row
    int rsub = tid >> 2;  // row within group of 64
    const float4* w4 = (const float4*)w;
    const float4* x4 = (const float4*)x;
    long long f0 = base * 4 + tid;

    if (base + CHUNK <= (long long)nrows) {
#pragma unroll
        for (int g = 0; g < GRP; g += 4) {
            float4 a0 = w4[f0 + (long long)(g + 0) * 256];
            float4 a1 = w4[f0 + (long long)(g + 1) * 256];
            float4 a2 = w4[f0 + (long long)(g + 2) * 256];
            float4 a3 = w4[f0 + (long long)(g + 3) * 256];
            float4 b0 = x4[f0 + (long long)(g + 0) * 256];
            float4 b1 = x4[f0 + (long long)(g + 1) * 256];
            float4 b2 = x4[f0 + (long long)(g + 2) * 256];
            float4 b3 = x4[f0 + (long long)(g + 3) * 256];
            double p0 = dot4d(a0, b0), p1 = dot4d(a1, b1);
            double p2 = dot4d(a2, b2), p3 = dot4d(a3, b3);
            p0 += __shfl_xor(p0, 1, 64); p0 += __shfl_xor(p0, 2, 64);
            p1 += __shfl_xor(p1, 1, 64); p1 += __shfl_xor(p1, 2, 64);
            p2 += __shfl_xor(p2, 1, 64); p2 += __shfl_xor(p2, 2, 64);
            p3 += __shfl_xor(p3, 1, 64); p3 += __shfl_xor(p3, 2, 64);
            if (q == 0) {
                Rs[(g + 0) * 64 + rsub] = (float)p0;
                Rs[(g + 1) * 64 + rsub] = (float)p1;
                Rs[(g + 2) * 64 + rsub] = (float)p2;
                Rs[(g + 3) * 64 + rsub] = (float)p3;
            }
        }
    } else {
        for (int g = 0; g < GRP; ++g) {
            long long row = base + g * 64 + rsub;
            double p = 0.0;
            if (row < nrows) {
                float4 a = w4[row * 4 + q];
                float4 b = x4[row * 4 + q];
                p = dot4d(a, b);
            }
            p += __shfl_xor(p, 1, 64);
            p += __shfl_xor(p, 2, 64);
            if (q == 0) Rs[g * 64 + rsub] = (float)p;
        }
    }
    __syncthreads();

    // ---- phase 2: per-thread segment transform + block scan ----
    int start = tid * LPT;
    long long rem = (long long)nrows - (base + start);
    int len = rem >= LPT ? LPT : (rem > 0 ? (int)rem : 0);

    double m = 1.0, sA = 0.0, sB = 0.0;
    for (int k = 0; k < len; ++k) {
        double r = (double)Rs[start + k];
        sA = D_C * sA + D_ETA * r;
        sB = D_C * sB + D_ETA * (r * r);
        m *= D_C;
    }
    block_scan(m, sA, sB, mS, aS, bS);
    // thread BLOCK-1 now holds the chunk aggregate transform (m, sA, sB).

    // ---- phase 3: publish aggregate, decoupled lookback ----
    if (tid == BLOCK - 1) {
        double* rc = recs + (size_t)cid * 6;
        __hip_atomic_store(&rc[0], m,  __ATOMIC_RELAXED, SCOPE);
        __hip_atomic_store(&rc[1], sA, __ATOMIC_RELAXED, SCOPE);
        __hip_atomic_store(&rc[2], sB, __ATOMIC_RELAXED, SCOPE);
        __hip_atomic_store(&flags[cid], 1u, __ATOMIC_RELEASE, SCOPE);

        double cm = 1.0, ca = 0.0, cb = 0.0;  // product of earlier transforms
        for (int j = cid - 1; j >= 0; --j) {
            unsigned f;
            while ((f = __hip_atomic_load(&flags[j], __ATOMIC_ACQUIRE, SCOPE)) == 0u)
                __builtin_amdgcn_s_sleep(2);
            const double* rj = recs + (size_t)j * 6 + (f == 2u ? 3 : 0);
            double jm = __hip_atomic_load(&rj[0], __ATOMIC_RELAXED, SCOPE);
            double ja = __hip_atomic_load(&rj[1], __ATOMIC_RELAXED, SCOPE);
            double jb = __hip_atomic_load(&rj[2], __ATOMIC_RELAXED, SCOPE);
            // cur = cur ∘ T_j  (T_j applied first)
            ca = cm * ja + ca;
            cb = cm * jb + cb;
            cm = cm * jm;
            if (f == 2u) break;   // rj was an inclusive prefix: done
        }
        // publish own inclusive prefix P = T_own ∘ cur
        __hip_atomic_store(&rc[3], m * cm,       __ATOMIC_RELAXED, SCOPE);
        __hip_atomic_store(&rc[4], m * ca + sA,  __ATOMIC_RELAXED, SCOPE);
        __hip_atomic_store(&rc[5], m * cb + sB,  __ATOMIC_RELAXED, SCOPE);
        __hip_atomic_store(&flags[cid], 2u, __ATOMIC_RELEASE, SCOPE);
        // block start state = cur applied to (A=0, B=eps)
        exA = ca;
        exB = cm * D_EPS + cb;
    }
    __syncthreads();

    // ---- phase 4: replay D over own segment ----
    double em = 1.0, ea = 0.0, eb = 0.0;
    if (tid > 0) { em = mS[tid - 1]; ea = aS[tid - 1]; eb = bS[tid - 1]; }
    double A = em * exA + ea;
    double B = em * exB + eb;

    double dsum = 0.0;
    for (int k = 0; k < len; ++k) {
        double r = (double)Rs[start + k];
        double dA = D_ETA * (r - A);
        double dB = D_ETA * (r * r - B);
        double var = B - A * A;
        if (var < D_EPS) var = D_EPS;
        double denom = var * sqrt(var);
        dsum += (B * dA - 0.5 * A * dB) / denom;
        A += dA;
        B += dB;
    }

#pragma unroll
    for (int off = 32; off > 0; off >>= 1) dsum += __shfl_down(dsum, off, 64);
    if ((tid & 63) == 0) wsum[tid >> 6] = dsum;
    __syncthreads();

    // ---- phase 5: global accumulate; last block writes output ----
    if (tid == 0) {
        double bs = wsum[0] + wsum[1] + wsum[2] + wsum[3];
        __hip_atomic_fetch_add(acc, bs, __ATOMIC_RELAXED, SCOPE);
        unsigned r = __hip_atomic_fetch_add(done, 1u, __ATOMIC_ACQ_REL, SCOPE);
        if (r == (unsigned)(nb - 1)) {
            double total = __hip_atomic_load(acc, __ATOMIC_RELAXED, SCOPE);
            out[0] = (float)(-total / (double)nrows);
        }
    }
}

extern "C" void kernel_launch(void* const* d_in, const int* in_sizes, int n_in,
                              void* d_out, int out_size, void* d_ws, size_t ws_size,
                              hipStream_t stream)
{
    const float* w = (const float*)d_in[0];
    const float* x = (const float*)d_in[1];
    int nrows = in_sizes[0] / 16;
    int nb = (nrows + CHUNK - 1) / CHUNK;

    // ws layout (all zero-inited by k0 where needed):
    //   [0]          ticket (u32)
    //   [1]          done   (u32)
    //   [2..3]       acc    (f64, as 2 u32)
    //   [4..4+nb)    flags  (u32 each)
    //   then recs: nb*6 f64 (no init needed; flag-guarded)
    unsigned* ctl    = (unsigned*)d_ws;
    unsigned* ticket = ctl + 0;
    unsigned* done   = ctl + 1;
    double*   acc    = (double*)(ctl + 2);
    unsigned* flags  = ctl + 4;
    int nctl = 4 + nb;
    size_t recs_off = ((size_t)nctl * 4 + 255) & ~(size_t)255;
    double* recs = (double*)((char*)d_ws + recs_off);

    k0_init<<<(nctl + BLOCK - 1) / BLOCK, BLOCK, 0, stream>>>(ctl, nctl);
    k_mega<<<nb, BLOCK, 0, stream>>>(w, x, nrows, nb, ticket, flags, recs,
                                     acc, done, (float*)d_out);
}

// Round 5
// 311.436 us; speedup vs baseline: 1.9261x; 1.9261x over previous
//
#include <hip/hip_runtime.h>

// DSR loss: R_t = dot16(w_t,x_t); A_t = c*A_{t-1}+eta*R_t (c=0.99), B_t
// likewise with R^2; D_t from (A_prev,B_prev); out = -mean(D).
//
// R5: 3 kernels, no cross-block waiting (R4's lookback serialized at
// ~450ns/hop x 977 chunks).
//  k0: zero 16B control (acc,done).
//  k1: dots (lane-quad, 8 dwordx4 in flight) -> R to ws + per-chunk affine
//      aggregate via shuffle reduction (no block_scan, no scan LDS).
//  k2: replay: per-block redundant global prefix over all chunk aggregates
//      (wave0: 64 lanes x ~16 serial combines + 6 shuffle combines, ~1us,
//      fully parallel across blocks), intra-block scan, D replay, fp64
//      atomicAdd + done counter; last block writes the scalar.
// fp64 internal math (absmax 0.0 vs np ref in R1-R4).

#define D_ETA 0.01
#define D_C   (1.0 - D_ETA)
#define D_EPS 1e-8

constexpr int BLOCK = 256;
constexpr int CHUNK = 2048;          // rows per chunk
constexpr int LPT   = CHUNK / BLOCK; // 8 rows per thread
constexpr int GRP   = CHUNK / 64;    // 32 row-groups of 64

#define SCOPE __HIP_MEMORY_SCOPE_AGENT

__device__ __forceinline__ int pidx(int i) { return i + (i >> 3); }
constexpr int RS_SIZE = CHUNK + CHUNK / 8;

__device__ __forceinline__ double dot4d(float4 a, float4 b) {
    return (double)a.x * (double)b.x + (double)a.y * (double)b.y
         + (double)a.z * (double)b.z + (double)a.w * (double)b.w;
}

// fallback: fp64 dot for one row
__device__ __forceinline__ float row_R(const float* __restrict__ w,
                                       const float* __restrict__ x,
                                       long long row) {
    const float4* w4 = (const float4*)(w + row * 16);
    const float4* x4 = (const float4*)(x + row * 16);
    double r = 0.0;
#pragma unroll
    for (int q = 0; q < 4; ++q) r += dot4d(w4[q], x4[q]);
    return (float)r;
}

// ordered wave-64 reduction of affine transforms; lane 0 gets the
// composition T_{63} .. T_1 T_0 (lane order = row order, T0 first).
__device__ __forceinline__ void wave_combine(double& m, double& a, double& b) {
    int lane = threadIdx.x & 63;
#pragma unroll
    for (int off = 1; off < 64; off <<= 1) {
        double pm = __shfl_down(m, off, 64);
        double pa = __shfl_down(a, off, 64);
        double pb = __shfl_down(b, off, 64);
        if (lane + off < 64) {          // partner applied AFTER self
            a = pm * a + pa;
            b = pm * b + pb;
            m = pm * m;
        }
    }
}

// Hillis-Steele inclusive scan over 256 affine transforms.
__device__ __forceinline__ void block_scan(double& m, double& sA, double& sB,
                                           double* mS, double* aS, double* bS) {
    int tid = threadIdx.x;
    mS[tid] = m; aS[tid] = sA; bS[tid] = sB;
    __syncthreads();
#pragma unroll
    for (int off = 1; off < BLOCK; off <<= 1) {
        double pm = 1.0, pa = 0.0, pb = 0.0;
        if (tid >= off) { pm = mS[tid - off]; pa = aS[tid - off]; pb = bS[tid - off]; }
        __syncthreads();
        if (tid >= off) {
            sA = m * pa + sA;
            sB = m * pb + sB;
            m  = pm * m;
        }
        mS[tid] = m; aS[tid] = sA; bS[tid] = sB;
        __syncthreads();
    }
}

// ---------------- K0: zero control ----------------
__global__ __launch_bounds__(64) void k0_init(unsigned* __restrict__ ctl)
{
    if (threadIdx.x < 4) ctl[threadIdx.x] = 0u;
}

// ---------------- K1: dots + R + chunk aggregate ----------------
__global__ __launch_bounds__(BLOCK) void k1_dots_agg(
    const float* __restrict__ w, const float* __restrict__ x, int nrows,
    float* __restrict__ Rws,          // may be null (fallback)
    double* __restrict__ aggs)        // [nb*3]
{
    __shared__ float Rs[RS_SIZE];
    __shared__ double wM[4], wA[4], wB[4];
    int tid = threadIdx.x;
    int q    = tid & 3;
    int rsub = tid >> 2;
    long long base = (long long)blockIdx.x * CHUNK;
    const float4* w4 = (const float4*)w;
    const float4* x4 = (const float4*)x;
    long long f0 = base * 4 + tid;

    if (base + CHUNK <= (long long)nrows) {
#pragma unroll
        for (int g = 0; g < GRP; g += 4) {
            float4 a0 = w4[f0 + (long long)(g + 0) * 256];
            float4 a1 = w4[f0 + (long long)(g + 1) * 256];
            float4 a2 = w4[f0 + (long long)(g + 2) * 256];
            float4 a3 = w4[f0 + (long long)(g + 3) * 256];
            float4 b0 = x4[f0 + (long long)(g + 0) * 256];
            float4 b1 = x4[f0 + (long long)(g + 1) * 256];
            float4 b2 = x4[f0 + (long long)(g + 2) * 256];
            float4 b3 = x4[f0 + (long long)(g + 3) * 256];
            double p0 = dot4d(a0, b0), p1 = dot4d(a1, b1);
            double p2 = dot4d(a2, b2), p3 = dot4d(a3, b3);
            p0 += __shfl_xor(p0, 1, 64); p0 += __shfl_xor(p0, 2, 64);
            p1 += __shfl_xor(p1, 1, 64); p1 += __shfl_xor(p1, 2, 64);
            p2 += __shfl_xor(p2, 1, 64); p2 += __shfl_xor(p2, 2, 64);
            p3 += __shfl_xor(p3, 1, 64); p3 += __shfl_xor(p3, 2, 64);
            if (q == 0) {
                Rs[pidx((g + 0) * 64 + rsub)] = (float)p0;
                Rs[pidx((g + 1) * 64 + rsub)] = (float)p1;
                Rs[pidx((g + 2) * 64 + rsub)] = (float)p2;
                Rs[pidx((g + 3) * 64 + rsub)] = (float)p3;
                if (Rws) {
                    Rws[base + (g + 0) * 64 + rsub] = (float)p0;
                    Rws[base + (g + 1) * 64 + rsub] = (float)p1;
                    Rws[base + (g + 2) * 64 + rsub] = (float)p2;
                    Rws[base + (g + 3) * 64 + rsub] = (float)p3;
                }
            }
        }
    } else {
        for (int g = 0; g < GRP; ++g) {
            long long row = base + g * 64 + rsub;
            double p = 0.0;
            if (row < nrows) p = dot4d(w4[row * 4 + q], x4[row * 4 + q]);
            p += __shfl_xor(p, 1, 64);
            p += __shfl_xor(p, 2, 64);
            if (q == 0) {
                Rs[pidx(g * 64 + rsub)] = (float)p;
                if (Rws && row < nrows) Rws[row] = (float)p;
            }
        }
    }
    __syncthreads();

    // per-thread segment transform over 8 rows
    int start = tid * LPT;
    long long rem = (long long)nrows - (base + start);
    int len = rem >= LPT ? LPT : (rem > 0 ? (int)rem : 0);
    double m = 1.0, sA = 0.0, sB = 0.0;
    for (int k = 0; k < len; ++k) {
        double r = (double)Rs[pidx(start + k)];
        sA = D_C * sA + D_ETA * r;
        sB = D_C * sB + D_ETA * (r * r);
        m *= D_C;
    }
    wave_combine(m, sA, sB);
    int wv = tid >> 6;
    if ((tid & 63) == 0) { wM[wv] = m; wA[wv] = sA; wB[wv] = sB; }
    __syncthreads();
    if (tid == 0) {
        double cm = wM[0], ca = wA[0], cb = wB[0];
#pragma unroll
        for (int v = 1; v < 4; ++v) {       // wave v applied after wave v-1
            ca = wM[v] * ca + wA[v];
            cb = wM[v] * cb + wB[v];
            cm = wM[v] * cm;
        }
        double* ag = aggs + (size_t)blockIdx.x * 3;
        ag[0] = cm; ag[1] = ca; ag[2] = cb;
    }
}

// ---------------- K2: prefix + replay + accumulate ----------------
__global__ __launch_bounds__(BLOCK) void k2_replay(
    const float* __restrict__ Rws,    // may be null (fallback)
    const float* __restrict__ w, const float* __restrict__ x, int nrows,
    const double* __restrict__ aggs, int nb,
    double* __restrict__ acc, unsigned* __restrict__ done,
    float* __restrict__ out)
{
    __shared__ double mS[BLOCK], aS[BLOCK], bS[BLOCK];
    __shared__ double exAB[2];
    __shared__ double wsum[BLOCK / 64];
    int tid = threadIdx.x;
    int cid = blockIdx.x;
    long long base = (long long)cid * CHUNK;
    long long g0 = base + (long long)tid * LPT;
    long long rem = (long long)nrows - g0;
    int len = rem >= LPT ? LPT : (rem > 0 ? (int)rem : 0);

    float rv[LPT];
    if (Rws) {
        if (len == LPT) {
            const float4* Rp = (const float4*)(Rws + g0);
            float4 u = Rp[0], v = Rp[1];
            rv[0]=u.x; rv[1]=u.y; rv[2]=u.z; rv[3]=u.w;
            rv[4]=v.x; rv[5]=v.y; rv[6]=v.z; rv[7]=v.w;
        } else {
            for (int k = 0; k < len; ++k) rv[k] = Rws[g0 + k];
        }
    } else {
        for (int k = 0; k < len; ++k) rv[k] = row_R(w, x, g0 + k);
    }

    // intra-block scan of per-thread transforms
    double m = 1.0, sA = 0.0, sB = 0.0;
    for (int k = 0; k < len; ++k) {
        double r = (double)rv[k];
        sA = D_C * sA + D_ETA * r;
        sB = D_C * sB + D_ETA * (r * r);
        m *= D_C;
    }
    block_scan(m, sA, sB, mS, aS, bS);

    // wave 0: global exclusive prefix over aggs[0..cid)
    if (tid < 64) {
        int K = (cid + 63) >> 6;     // aggs per lane (0 if cid==0)
        int lo = tid * K;
        int hi = lo + K; if (hi > cid) hi = cid;
        double pm = 1.0, pa = 0.0, pb = 0.0;
        for (int j = lo; j < hi; ++j) {
            const double* ag = aggs + (size_t)j * 3;
            double jm = ag[0], ja = ag[1], jb = ag[2];
            pa = jm * pa + ja;       // T_j applied after previous
            pb = jm * pb + jb;
            pm = jm * pm;
        }
        wave_combine(pm, pa, pb);
        if (tid == 0) {
            exAB[0] = pa;                 // A0 = pm*0 + pa
            exAB[1] = pm * D_EPS + pb;    // B0 = pm*eps + pb
        }
    }
    __syncthreads();

    double em = 1.0, ea = 0.0, eb = 0.0;
    if (tid > 0) { em = mS[tid - 1]; ea = aS[tid - 1]; eb = bS[tid - 1]; }
    double A = em * exAB[0] + ea;
    double B = em * exAB[1] + eb;

    double dsum = 0.0;
    for (int k = 0; k < len; ++k) {
        double r = (double)rv[k];
        double dA = D_ETA * (r - A);
        double dB = D_ETA * (r * r - B);
        double var = B - A * A;
        if (var < D_EPS) var = D_EPS;
        double denom = var * sqrt(var);
        dsum += (B * dA - 0.5 * A * dB) / denom;
        A += dA;
        B += dB;
    }

#pragma unroll
    for (int off = 32; off > 0; off >>= 1) dsum += __shfl_down(dsum, off, 64);
    if ((tid & 63) == 0) wsum[tid >> 6] = dsum;
    __syncthreads();

    if (tid == 0) {
        double bs = wsum[0] + wsum[1] + wsum[2] + wsum[3];
        __hip_atomic_fetch_add(acc, bs, __ATOMIC_RELAXED, SCOPE);
        unsigned r = __hip_atomic_fetch_add(done, 1u, __ATOMIC_ACQ_REL, SCOPE);
        if (r == (unsigned)(nb - 1)) {
            double total = __hip_atomic_load(acc, __ATOMIC_RELAXED, SCOPE);
            out[0] = (float)(-total / (double)nrows);
        }
    }
}

extern "C" void kernel_launch(void* const* d_in, const int* in_sizes, int n_in,
                              void* d_out, int out_size, void* d_ws, size_t ws_size,
                              hipStream_t stream)
{
    const float* w = (const float*)d_in[0];
    const float* x = (const float*)d_in[1];
    int nrows = in_sizes[0] / 16;
    int nb = (nrows + CHUNK - 1) / CHUNK;

    // ws layout: [acc f64 | done u32 | pad to 64] [aggs nb*3 f64] [R floats]
    unsigned* ctl  = (unsigned*)d_ws;
    double*   acc  = (double*)d_ws;
    unsigned* done = ctl + 2;
    double*   aggs = (double*)((char*)d_ws + 64);
    size_t roff = (64 + (size_t)nb * 3 * sizeof(double) + 255) & ~(size_t)255;
    float* Rws = nullptr;
    if (ws_size >= roff + (size_t)nrows * sizeof(float))
        Rws = (float*)((char*)d_ws + roff);

    k0_init<<<1, 64, 0, stream>>>(ctl);
    k1_dots_agg<<<nb, BLOCK, 0, stream>>>(w, x, nrows, Rws, aggs);
    k2_replay<<<nb, BLOCK, 0, stream>>>(Rws, w, x, nrows, aggs, nb,
                                        acc, done, (float*)d_out);
}